// Round 2
// baseline (104.477 us; speedup 1.0000x reference)
//
#include <hip/hip_runtime.h>
#include <math.h>

#define B_ 32
#define N_ 2048
#define M_ 16
#define K_ 32
#define EPS 1e-12f

constexpr int NC      = 128;              // rows per chunk
constexpr int NCHUNK  = N_ / NC;          // 16
constexpr int TPB     = 1024;             // 16 waves; thread = (k 0..31) x (grp 0..31)
constexpr int NWAVE   = TPB / 64;         // 16
constexpr int YSTRIDE = 20;               // padded row stride: 80 B, 16B-aligned, non-pow2
constexpr int F4      = NC * (M_ + 1) / 4; // 544 float4 per chunk

// fast atanh: 0.5*ln((1+x)/(1-x)); x in [0, 1-1e-5] -> rcp arg >= 1e-5, safe.
__device__ __forceinline__ float fast_atanh(float x) {
    float ratio = (1.0f + x) * __builtin_amdgcn_rcpf(1.0f - x);
    return 0.34657359f * __log2f(ratio);
}

// ---------------- single-dispatch kernel: one block per batch ----------------
// Each block (batch b): loops over 16 chunks of 128 rows with double-buffered
// LDS staging (prefetch chunk c+1 into registers while computing chunk c),
// tracks the global first-invalid prefix (validity is a cumprod), accumulates
// G[k][m] = sum_n w*coef*y, then runs the per-batch epilogue in-block.
// No workspace, no second kernel, no inter-block communication.
__global__ __launch_bounds__(TPB) void pml_onepass_kernel(
    const float* __restrict__ dgm, const float* __restrict__ theta,
    const float* __restrict__ class_w, float* __restrict__ out)
{
    __shared__ __align__(16) float y_lds[2][NC * YSTRIDE];   // 20 KB
    __shared__ float hom_lds[2][NC];
    __shared__ float w_lds[NC];
    __shared__ unsigned wred[2];
    __shared__ float red[NWAVE][K_ * (M_ + 1)];              // 34 KB, stride-17
    __shared__ float S_lds[K_ * M_];                         // 2 KB

    const int b    = blockIdx.x;
    const int tid  = threadIdx.x;
    const int k    = tid & (K_ - 1);
    const int grp  = tid >> 5;        // 0..31
    const int lane = tid & 63;
    const int wv   = tid >> 6;        // 0..15

    const float4* src4 = (const float4*)(dgm + (size_t)b * N_ * (M_ + 1));

    // scatter one float4 of the packed (row,17) stream into padded LDS buf p
    auto scatter = [&](int p, float4 v, int i4) {
        int i  = i4 * 4;
        int nl = i / (M_ + 1);
        int j  = i - nl * (M_ + 1);
        float vv[4] = { v.x, v.y, v.z, v.w };
#pragma unroll
        for (int e = 0; e < 4; ++e) {
            if (j == 0) hom_lds[p][nl] = vv[e];
            else        y_lds[p][nl * YSTRIDE + (j - 1)] = vv[e];
            if (++j == M_ + 1) { j = 0; ++nl; }
        }
    };

    // ---- prologue: stage chunk 0 ----
    if (tid < F4) scatter(0, src4[tid], tid);

    // theta fragment for this thread's k (L2-hot, 16 scalar loads)
    float t2[M_];
#pragma unroll
    for (int m = 0; m < M_; ++m) { float t = theta[k * M_ + m]; t2[m] = t * t; }
    const float cw0 = class_w[0], cw1 = class_w[1];

    float g[M_];
#pragma unroll
    for (int m = 0; m < M_; ++m) g[m] = 0.0f;

    __syncthreads();

    int p = 0, c = 0;
    for (;;) {
        // 1. prefetch chunk c+1 into registers (latency hides under compute)
        float4 vpre;
        const bool have = (c + 1 < NCHUNK) && (tid < F4);
        if (have) vpre = src4[(c + 1) * F4 + tid];

        // 2. validity scan + weights for chunk c (threads 0..127, waves 0,1 full)
        if (tid < NC) {
            const float4* yv = (const float4*)(y_lds[p] + tid * YSTRIDE);
            float4 a0 = yv[0], a1 = yv[1], a2 = yv[2], a3 = yv[3];
            float  h  = hom_lds[p][tid];
            bool nz = (h != 0.0f) |
                      (a0.x != 0.0f) | (a0.y != 0.0f) | (a0.z != 0.0f) | (a0.w != 0.0f) |
                      (a1.x != 0.0f) | (a1.y != 0.0f) | (a1.z != 0.0f) | (a1.w != 0.0f) |
                      (a2.x != 0.0f) | (a2.y != 0.0f) | (a2.z != 0.0f) | (a2.w != 0.0f) |
                      (a3.x != 0.0f) | (a3.y != 0.0f) | (a3.z != 0.0f) | (a3.w != 0.0f);
            bool ok = ((int)h <= 1) && nz;
            unsigned long long bal = __ballot(!ok);
            if (lane == 0)
                wred[wv] = bal ? (unsigned)(wv * 64 + (__ffsll((long long)bal) - 1))
                               : 0xFFFFFFFFu;
            int hc = min(max((int)h, 0), 1);
            w_lds[tid] = hc ? cw1 : cw0;
        }
        __syncthreads();
        const int local_mn = (int)min(min(wred[0], wred[1]), (unsigned)NC);

        // 3. accumulate rows grp, grp+32, grp+64, grp+96 (< local_mn)
        for (int nl = grp; nl < local_mn; nl += 32) {
            float w = w_lds[nl];                                          // broadcast
            const float4* yv = (const float4*)(y_lds[p] + nl * YSTRIDE);  // broadcast
            float4 a0 = yv[0], a1 = yv[1], a2 = yv[2], a3 = yv[3];
            float y[M_] = { a0.x, a0.y, a0.z, a0.w,  a1.x, a1.y, a1.z, a1.w,
                            a2.x, a2.y, a2.z, a2.w,  a3.x, a3.y, a3.z, a3.w };
            float s = 0.0f;
#pragma unroll
            for (int m = 0; m < M_; ++m) s = fmaf(y[m] * y[m], t2[m], s);
            float d   = 1.0f + sqrtf(1.0f + s + EPS);
            float rd  = __builtin_amdgcn_rcpf(d);
            float xn2 = fmaf(s, rd * rd, EPS);
            float xn  = sqrtf(xn2);
            float inv_xnd = __builtin_amdgcn_rsqf(xn2) * rd;   // 1/(xn*d)
            float xc  = fminf(xn, 1.0f - 1e-5f);
            float wc  = w * (fast_atanh(xc) * inv_xnd);
#pragma unroll
            for (int m = 0; m < M_; ++m) g[m] = fmaf(wc, y[m], g[m]);
        }

        // 4. commit prefetch, advance (local_mn uniform -> uniform exit)
        const bool done = (local_mn < NC) || (c + 1 == NCHUNK);
        if (done) break;
        if (have) scatter(p ^ 1, vpre, tid);
        __syncthreads();
        p ^= 1; ++c;
    }

    // ---- reduce: lanes (k, k+32) in-wave, then 16 waves via LDS ----
#pragma unroll
    for (int m = 0; m < M_; ++m) g[m] += __shfl_down(g[m], 32, 64);
    if (lane < K_) {
#pragma unroll
        for (int m = 0; m < M_; ++m) red[wv][lane * (M_ + 1) + m] = g[m];
    }
    __syncthreads();

    for (int e = tid; e < K_ * M_; e += TPB) {   // threads 0..511, one elem each
        int kk = e >> 4, m = e & 15;
        float s = 0.0f;
#pragma unroll
        for (int w = 0; w < NWAVE; ++w) s += red[w][kk * (M_ + 1) + m];
        S_lds[e] = s;                            // layout k*16+m
    }
    __syncthreads();

    // ---- epilogue: wave 0, lanes 0..31 (lane = k) ----
    if (tid < K_) {
        const int klane = tid;
        float S[M_];
#pragma unroll
        for (int m = 0; m < M_; ++m)
            S[m] = theta[klane * M_ + m] * S_lds[klane * M_ + m];

        // inclusive prefix sum over k within the 32-lane segment
#pragma unroll
        for (int m = 0; m < M_; ++m) {
            float v = S[m];
#pragma unroll
            for (int off = 1; off < K_; off <<= 1) {
                float up = __shfl_up(v, off, 32);
                if (klane >= off) v += up;
            }
            S[m] = v;
        }

        float sn2 = 0.0f;
#pragma unroll
        for (int m = 0; m < M_; ++m) sn2 = fmaf(S[m], S[m], sn2);
        float Sn = sqrtf(sn2 + EPS);
        float e2 = __expf(-2.0f * Sn);
        float r  = (1.0f - e2) * __builtin_amdgcn_rcpf((1.0f + e2) * Sn);

        float xd[M_];
        float xdn2 = 0.0f;
#pragma unroll
        for (int m = 0; m < M_; ++m) { xd[m] = r * S[m]; xdn2 = fmaf(xd[m], xd[m], xdn2); }
        float scale = 2.0f / fmaxf(1.0f - xdn2, 1e-7f);

#pragma unroll
        for (int m = 0; m < M_; ++m)
            out[(size_t)b * (K_ * M_) + klane * M_ + m] = scale * xd[m];
    }
}

extern "C" void kernel_launch(void* const* d_in, const int* in_sizes, int n_in,
                              void* d_out, int out_size, void* d_ws, size_t ws_size,
                              hipStream_t stream) {
    const float* dgm     = (const float*)d_in[0];   // (B, N, 17)
    const float* theta   = (const float*)d_in[1];   // (K, M)
    const float* class_w = (const float*)d_in[2];   // (2,)
    float* out = (float*)d_out;                     // (B, K*M) f32

    // single plain dispatch; no workspace, no inter-block dependencies
    pml_onepass_kernel<<<B_, TPB, 0, stream>>>(dgm, theta, class_w, out);
}